// Round 6
// baseline (5913.582 us; speedup 1.0000x reference)
//
#include <hip/hip_runtime.h>

typedef unsigned int u32;
typedef unsigned short u16;
typedef unsigned long long u64;
typedef __attribute__((ext_vector_type(8))) short v8s;   // 8 bf16
typedef __attribute__((ext_vector_type(4))) float v4f;
typedef __attribute__((ext_vector_type(2))) float v2f;
typedef __attribute__((ext_vector_type(4))) u32 v4u;

#define VALIDMASK 0x0001000100010001ULL

__device__ __forceinline__ float bf2f(u16 v) { return __uint_as_float(((u32)v) << 16); }
__device__ __forceinline__ u16 f2bf(float f) {
    u32 u = __float_as_uint(f);
    return (u16)((u + 0x7fffu + ((u >> 16) & 1u)) >> 16);   // RNE
}
// truncate-to-odd bf16: LSB always 1 (valid bit), |err| <= 1 ulp
__device__ __forceinline__ u32 f2bfo(float f) { return (__float_as_uint(f) >> 16) | 1u; }
__device__ __forceinline__ float blo(u32 u) { return __uint_as_float(u << 16); }
__device__ __forceinline__ float bhi(u32 u) { return __uint_as_float(u & 0xffff0000u); }
__device__ __forceinline__ float sigf(float x) { return 1.0f / (1.0f + __expf(-x)); }
__device__ __forceinline__ float tanhfast(float x) {
    float e = __expf(2.0f * x);
    return 1.0f - 2.0f / (e + 1.0f);
}
__device__ __forceinline__ v8s pack8(v4f a, v4f b) {
    v8s r;
    r[0] = (short)f2bf(a[0]); r[1] = (short)f2bf(a[1]);
    r[2] = (short)f2bf(a[2]); r[3] = (short)f2bf(a[3]);
    r[4] = (short)f2bf(b[0]); r[5] = (short)f2bf(b[1]);
    r[6] = (short)f2bf(b[2]); r[7] = (short)f2bf(b[3]);
    return r;
}

// ---------------------------------------------------------------------------
// GEMM: out[t][j] = sum_k A[t][k]*W[j][k] + bih[j] + bhh[j]. fp32 in, bf16 out.
// Layer-0 input projections only (K=768).
// ---------------------------------------------------------------------------
__global__ __launch_bounds__(256) void gemm_ih(
    const float* __restrict__ A, const float* __restrict__ W,
    const float* __restrict__ bih, const float* __restrict__ bhh,
    u16* __restrict__ out, int K)
{
    __shared__ u16 As[128][40];
    __shared__ u16 Bs[128][40];
    const int tm = blockIdx.x, tn = blockIdx.y;
    const int tid = threadIdx.x;
    const int lane = tid & 63;
    const int wv = tid >> 6;
    const int wm = wv >> 1, wn = wv & 1;
    const int fr = lane & 15, fq = lane >> 4;

    v4f acc[4][4] = {};

    for (int kt = 0; kt < K; kt += 32) {
#pragma unroll
        for (int it = 0; it < 2; ++it) {
            int q = tid + it * 256;
            int r = q >> 2;
            int c8 = (q & 3) * 8;
            const float* pa = &A[(size_t)(tm * 128 + r) * K + kt + c8];
            const float* pw = &W[(size_t)(tn * 128 + r) * K + kt + c8];
            *(v8s*)&As[r][c8] = pack8(*(const v4f*)pa, *(const v4f*)(pa + 4));
            *(v8s*)&Bs[r][c8] = pack8(*(const v4f*)pw, *(const v4f*)(pw + 4));
        }
        __syncthreads();
        v8s af[4], bfr[4];
#pragma unroll
        for (int mi = 0; mi < 4; ++mi)
            af[mi] = *(const v8s*)&As[wm * 64 + mi * 16 + fr][fq * 8];
#pragma unroll
        for (int ni = 0; ni < 4; ++ni)
            bfr[ni] = *(const v8s*)&Bs[wn * 64 + ni * 16 + fr][fq * 8];
#pragma unroll
        for (int mi = 0; mi < 4; ++mi)
#pragma unroll
            for (int ni = 0; ni < 4; ++ni)
                acc[mi][ni] = __builtin_amdgcn_mfma_f32_16x16x32_bf16(af[mi], bfr[ni], acc[mi][ni], 0, 0, 0);
        __syncthreads();
    }

#pragma unroll
    for (int ni = 0; ni < 4; ++ni) {
        int col = tn * 128 + wn * 64 + ni * 16 + fr;
        float bias = bih[col] + bhh[col];
#pragma unroll
        for (int mi = 0; mi < 4; ++mi)
#pragma unroll
            for (int j = 0; j < 4; ++j) {
                int row = tm * 128 + wm * 64 + mi * 16 + fq * 4 + j;
                out[(size_t)row * 4096 + col] = f2bf(acc[mi][ni][j] + bias);
            }
    }
}

// ---------------------------------------------------------------------------
// Fused persistent bidirectional 2-layer LSTM scan. 512 WGs (2/CU).
// role = bid>>8 (0: layer0, 1: layer1), d = (bid>>7)&1, wg = bid&127.
// WG owns 8 h-elements (32 Whh rows, bf16 in LDS). Layer-1 also holds its
// 32 Wih1 rows in registers and consumes h0 straight from layer-0's
// broadcast. Broadcast: 4 odd-LSB bf16 per u64 (valid bit = LSB of each
// half-word), relaxed agent atomics. Detection: per-(group,step) relaxed
// fetch_add counter (1 line) polled by one lane per wave -> slot burst-load
// once, valid-bit retry covers counter/data reordering.
// ---------------------------------------------------------------------------
__global__ __launch_bounds__(256, 2) void lstm_fused(
    const float* __restrict__ fw0_Whh, const float* __restrict__ bw0_Whh,
    const float* __restrict__ fw1_Whh, const float* __restrict__ bw1_Whh,
    const float* __restrict__ fw1_Wih, const float* __restrict__ bw1_Wih,
    const float* __restrict__ fw1_bih, const float* __restrict__ fw1_bhh,
    const float* __restrict__ bw1_bih, const float* __restrict__ bw1_bhh,
    const u16*  __restrict__ precomp0,   // [2][1024][4096] bf16
    u64* htag0,                          // [2][1024][256]
    u64* htag1,                          // [2][1024][256]
    u32* cnt,                            // [4][1024][32] (128B-strided counters)
    float* __restrict__ out)             // d_out base
{
    extern __shared__ char smem[];
    float* hA_sh     = (float*)(smem + 65536);  // 1280 (own-layer h, pad 2/8)
    float* hB_sh     = hA_sh + 1280;            // 1280 (h0 input, L1 only)
    float* gates_lds = hB_sh + 1280;            // 32
    float* c_lds     = gates_lds + 32;          // 8
    float* h_lds     = c_lds + 8;               // 8
    float* bias_lds  = h_lds + 8;               // 32

    const int tid = threadIdx.x;
    const int lane = tid & 63;
    const int w = tid >> 6;
    const int bid = blockIdx.x;
    const int role = bid >> 8;
    const int sub = bid & 255;
    const int d = sub >> 7;
    const int wg = sub & 127;
    const int e0 = wg << 3;

    const float* __restrict__ Whh =
        role ? (d ? bw1_Whh : fw1_Whh) : (d ? bw0_Whh : fw0_Whh);

    // Whh slice (32 rows x 1024) fp32 -> bf16 LDS, layout [gate][ei][1024].
#pragma unroll
    for (int it = 0; it < 16; ++it) {
        int q = tid + (it << 8);
        int g = q >> 10, ei = (q >> 7) & 7, cc = (q & 127) << 3;
        const float* pw = &Whh[(size_t)(g * 1024 + e0 + ei) * 1024 + cc];
        *(v8s*)(smem + (size_t)q * 16) = pack8(*(const v4f*)pw, *(const v4f*)(pw + 4));
    }

    // Layer-1: Wih1 slice -> registers (64 VGPR/lane), biases -> LDS.
    v4u wbuf[16];
    if (role) {
        const float* __restrict__ Wih = d ? bw1_Wih : fw1_Wih;
#pragma unroll
        for (int i = 0; i < 16; ++i) {
            int ei = i >> 1, c0 = ((i & 1) << 9) + (lane << 3);
            const float* p = &Wih[(size_t)(w * 1024 + e0 + ei) * 1024 + c0];
            v8s t = pack8(*(const v4f*)p, *(const v4f*)(p + 4));
            wbuf[i] = *(v4u*)&t;
        }
        if (tid < 32) {
            const float* bi = d ? bw1_bih : fw1_bih;
            const float* bh = d ? bw1_bhh : fw1_bhh;
            int g = tid >> 3, e = tid & 7;
            bias_lds[tid] = bi[g * 1024 + e0 + e] + bh[g * 1024 + e0 + e];
        }
    }
    if (tid < 8) c_lds[tid] = 0.0f;
    __syncthreads();

    const char* wbase = smem + w * 16384 + lane * 16;
    u64* hown = (role ? htag1 : htag0) + (size_t)d * 1024 * 256;
    u64* hin  = htag0 + (size_t)d * 1024 * 256;
    u32* cnt_own = cnt + ((size_t)(role * 2 + d) * 1024) * 32;   // own group
    u32* cnt_in  = cnt + ((size_t)d * 1024) * 32;                // layer-0 group

    float* cm_out = out + role * 2048;
    float* hs_out = out + 4096 + role * 2048;
    float* seq_out = out + 8192;    // [1024][2048], role 1 writes

    const int ip = (tid << 2) + ((tid >> 1) << 1);  // padded LDS index for e=4*tid

    if (role == 0) {
        // ------------------------- layer 0 scan -------------------------
        for (int s = 0; s < 1024; ++s) {
            // Prefetch precomp row (raw u16; convert only at use).
            u16 ri = 0, rf = 0, rg = 0, ro = 0;
            if (tid < 8) {
                int sx = d ? (1023 - s) : s;
                const u16* pr = precomp0 + ((size_t)d * 1024 + sx) * 4096 + e0 + tid;
                ri = pr[0]; rf = pr[1024]; rg = pr[2048]; ro = pr[3072];
            }
            float acc[8] = {0, 0, 0, 0, 0, 0, 0, 0};
            if (s > 0) {
                // Gate: one 4B counter line instead of 32 data lines.
                u32* cs = cnt_own + (size_t)(s - 1) * 32;
                u32 cv;
                do {
                    u32 t0 = 0;
                    if (lane == 0)
                        t0 = __hip_atomic_load(cs, __ATOMIC_RELAXED, __HIP_MEMORY_SCOPE_AGENT);
                    cv = (u32)__shfl((int)t0, 0, 64);
                    if (cv < 128u) __builtin_amdgcn_s_sleep(2);
                } while (cv < 128u);
                // Data burst (once), valid-bit retry covers reordering.
                u64* slot = hown + (size_t)(s - 1) * 256 + tid;
                u64 v = __hip_atomic_load(slot, __ATOMIC_RELAXED, __HIP_MEMORY_SCOPE_AGENT);
                while ((v & VALIDMASK) != VALIDMASK) {
                    __builtin_amdgcn_s_sleep(1);
                    v = __hip_atomic_load(slot, __ATOMIC_RELAXED, __HIP_MEMORY_SCOPE_AGENT);
                }
                u32 lo = (u32)v, hi = (u32)(v >> 32);
                hA_sh[ip]     = blo(lo); hA_sh[ip + 1] = bhi(lo);
                hA_sh[ip + 2] = blo(hi); hA_sh[ip + 3] = bhi(hi);
                __syncthreads();

                float hh[16];
                const float* g0 = &hA_sh[lane * 10];
                const float* g1 = &hA_sh[640 + lane * 10];
#pragma unroll
                for (int j2 = 0; j2 < 4; ++j2) {
                    *(v2f*)&hh[j2 * 2]     = *(const v2f*)&g0[j2 * 2];
                    *(v2f*)&hh[8 + j2 * 2] = *(const v2f*)&g1[j2 * 2];
                }
#pragma unroll
                for (int i = 0; i < 16; ++i) {
                    v4u wv4 = *(const v4u*)(wbase + i * 1024);
                    const int r = i >> 1;
                    const float* hp = &hh[(i & 1) * 8];
                    acc[r] = fmaf(blo(wv4[0]), hp[0], acc[r]);
                    acc[r] = fmaf(bhi(wv4[0]), hp[1], acc[r]);
                    acc[r] = fmaf(blo(wv4[1]), hp[2], acc[r]);
                    acc[r] = fmaf(bhi(wv4[1]), hp[3], acc[r]);
                    acc[r] = fmaf(blo(wv4[2]), hp[4], acc[r]);
                    acc[r] = fmaf(bhi(wv4[2]), hp[5], acc[r]);
                    acc[r] = fmaf(blo(wv4[3]), hp[6], acc[r]);
                    acc[r] = fmaf(bhi(wv4[3]), hp[7], acc[r]);
                }
            }
#pragma unroll
            for (int r = 0; r < 8; ++r) {
                float v = acc[r];
#pragma unroll
                for (int off = 32; off > 0; off >>= 1) v += __shfl_xor(v, off, 64);
                if (lane == 0) gates_lds[w * 8 + r] = v;
            }
            __syncthreads();

            if (tid < 8) {
                float Gi = gates_lds[tid]      + bf2f(ri);
                float Gf = gates_lds[8 + tid]  + bf2f(rf);
                float Gg = gates_lds[16 + tid] + bf2f(rg);
                float Go = gates_lds[24 + tid] + bf2f(ro);
                float c = sigf(Gf) * c_lds[tid] + sigf(Gi) * tanhfast(Gg);
                float h = sigf(Go) * tanhfast(c);
                c_lds[tid] = c;
                h_lds[tid] = h;
            }
            if (tid < 2) {   // publish slots, then lane0 bumps the counter
                int b = tid << 2;
                u32 lo = f2bfo(h_lds[b])     | (f2bfo(h_lds[b + 1]) << 16);
                u32 hi = f2bfo(h_lds[b + 2]) | (f2bfo(h_lds[b + 3]) << 16);
                u64 val = ((u64)hi << 32) | lo;
                __hip_atomic_store(&hown[(size_t)s * 256 + (e0 >> 2) + tid], val,
                                   __ATOMIC_RELAXED, __HIP_MEMORY_SCOPE_AGENT);
                if (tid == 0)
                    __hip_atomic_fetch_add(cnt_own + (size_t)s * 32, 1u,
                                           __ATOMIC_RELAXED, __HIP_MEMORY_SCOPE_AGENT);
            }
            if (tid < 8 && s == 1023) {
                cm_out[d * 1024 + e0 + tid] = c_lds[tid];
                hs_out[d * 1024 + e0 + tid] = h_lds[tid];
            }
        }
    } else {
        // ------------------------- layer 1 scan -------------------------
        for (int s = 0; s < 1024; ++s) {
            float acc[8] = {0, 0, 0, 0, 0, 0, 0, 0};
            {   // h0[s]: L0 runs ahead -> gate usually passes on first poll.
                u32* cs = cnt_in + (size_t)s * 32;
                u32 cv;
                do {
                    u32 t0 = 0;
                    if (lane == 0)
                        t0 = __hip_atomic_load(cs, __ATOMIC_RELAXED, __HIP_MEMORY_SCOPE_AGENT);
                    cv = (u32)__shfl((int)t0, 0, 64);
                    if (cv < 128u) __builtin_amdgcn_s_sleep(2);
                } while (cv < 128u);
                u64* slot = hin + (size_t)s * 256 + tid;
                u64 v = __hip_atomic_load(slot, __ATOMIC_RELAXED, __HIP_MEMORY_SCOPE_AGENT);
                while ((v & VALIDMASK) != VALIDMASK) {
                    __builtin_amdgcn_s_sleep(1);
                    v = __hip_atomic_load(slot, __ATOMIC_RELAXED, __HIP_MEMORY_SCOPE_AGENT);
                }
                u32 lo = (u32)v, hi = (u32)(v >> 32);
                hB_sh[ip]     = blo(lo); hB_sh[ip + 1] = bhi(lo);
                hB_sh[ip + 2] = blo(hi); hB_sh[ip + 3] = bhi(hi);
                __syncthreads();

                float hh0[16];
                const float* g0 = &hB_sh[lane * 10];
                const float* g1 = &hB_sh[640 + lane * 10];
#pragma unroll
                for (int j2 = 0; j2 < 4; ++j2) {
                    *(v2f*)&hh0[j2 * 2]     = *(const v2f*)&g0[j2 * 2];
                    *(v2f*)&hh0[8 + j2 * 2] = *(const v2f*)&g1[j2 * 2];
                }
                // Wih dot from registers — fills the h1[s-1] fabric window.
#pragma unroll
                for (int i = 0; i < 16; ++i) {
                    v4u wv4 = wbuf[i];
                    const int r = i >> 1;
                    const float* hp = &hh0[(i & 1) * 8];
                    acc[r] = fmaf(blo(wv4[0]), hp[0], acc[r]);
                    acc[r] = fmaf(bhi(wv4[0]), hp[1], acc[r]);
                    acc[r] = fmaf(blo(wv4[1]), hp[2], acc[r]);
                    acc[r] = fmaf(bhi(wv4[1]), hp[3], acc[r]);
                    acc[r] = fmaf(blo(wv4[2]), hp[4], acc[r]);
                    acc[r] = fmaf(bhi(wv4[2]), hp[5], acc[r]);
                    acc[r] = fmaf(blo(wv4[3]), hp[6], acc[r]);
                    acc[r] = fmaf(bhi(wv4[3]), hp[7], acc[r]);
                }
            }
            if (s > 0) {   // own recurrence h1[s-1]
                u32* cs = cnt_own + (size_t)(s - 1) * 32;
                u32 cv;
                do {
                    u32 t0 = 0;
                    if (lane == 0)
                        t0 = __hip_atomic_load(cs, __ATOMIC_RELAXED, __HIP_MEMORY_SCOPE_AGENT);
                    cv = (u32)__shfl((int)t0, 0, 64);
                    if (cv < 128u) __builtin_amdgcn_s_sleep(2);
                } while (cv < 128u);
                u64* slot = hown + (size_t)(s - 1) * 256 + tid;
                u64 v = __hip_atomic_load(slot, __ATOMIC_RELAXED, __HIP_MEMORY_SCOPE_AGENT);
                while ((v & VALIDMASK) != VALIDMASK) {
                    __builtin_amdgcn_s_sleep(1);
                    v = __hip_atomic_load(slot, __ATOMIC_RELAXED, __HIP_MEMORY_SCOPE_AGENT);
                }
                u32 lo = (u32)v, hi = (u32)(v >> 32);
                hA_sh[ip]     = blo(lo); hA_sh[ip + 1] = bhi(lo);
                hA_sh[ip + 2] = blo(hi); hA_sh[ip + 3] = bhi(hi);
                __syncthreads();

                float hh[16];
                const float* g0 = &hA_sh[lane * 10];
                const float* g1 = &hA_sh[640 + lane * 10];
#pragma unroll
                for (int j2 = 0; j2 < 4; ++j2) {
                    *(v2f*)&hh[j2 * 2]     = *(const v2f*)&g0[j2 * 2];
                    *(v2f*)&hh[8 + j2 * 2] = *(const v2f*)&g1[j2 * 2];
                }
#pragma unroll
                for (int i = 0; i < 16; ++i) {
                    v4u wv4 = *(const v4u*)(wbase + i * 1024);
                    const int r = i >> 1;
                    const float* hp = &hh[(i & 1) * 8];
                    acc[r] = fmaf(blo(wv4[0]), hp[0], acc[r]);
                    acc[r] = fmaf(bhi(wv4[0]), hp[1], acc[r]);
                    acc[r] = fmaf(blo(wv4[1]), hp[2], acc[r]);
                    acc[r] = fmaf(bhi(wv4[1]), hp[3], acc[r]);
                    acc[r] = fmaf(blo(wv4[2]), hp[4], acc[r]);
                    acc[r] = fmaf(bhi(wv4[2]), hp[5], acc[r]);
                    acc[r] = fmaf(blo(wv4[3]), hp[6], acc[r]);
                    acc[r] = fmaf(bhi(wv4[3]), hp[7], acc[r]);
                }
            }
#pragma unroll
            for (int r = 0; r < 8; ++r) {
                float v = acc[r];
#pragma unroll
                for (int off = 32; off > 0; off >>= 1) v += __shfl_xor(v, off, 64);
                if (lane == 0) gates_lds[w * 8 + r] = v;
            }
            __syncthreads();

            if (tid < 8) {
                float Gi = gates_lds[tid]      + bias_lds[tid];
                float Gf = gates_lds[8 + tid]  + bias_lds[8 + tid];
                float Gg = gates_lds[16 + tid] + bias_lds[16 + tid];
                float Go = gates_lds[24 + tid] + bias_lds[24 + tid];
                float c = sigf(Gf) * c_lds[tid] + sigf(Gi) * tanhfast(Gg);
                float h = sigf(Go) * tanhfast(c);
                c_lds[tid] = c;
                h_lds[tid] = h;
            }
            if (tid < 2) {
                int b = tid << 2;
                u32 lo = f2bfo(h_lds[b])     | (f2bfo(h_lds[b + 1]) << 16);
                u32 hi = f2bfo(h_lds[b + 2]) | (f2bfo(h_lds[b + 3]) << 16);
                u64 val = ((u64)hi << 32) | lo;
                __hip_atomic_store(&hown[(size_t)s * 256 + (e0 >> 2) + tid], val,
                                   __ATOMIC_RELAXED, __HIP_MEMORY_SCOPE_AGENT);
                if (tid == 0)
                    __hip_atomic_fetch_add(cnt_own + (size_t)s * 32, 1u,
                                           __ATOMIC_RELAXED, __HIP_MEMORY_SCOPE_AGENT);
            }
            if (tid < 8) {
                int rrow = d ? (1023 - s) : s;
                seq_out[(size_t)rrow * 2048 + d * 1024 + e0 + tid] = h_lds[tid];
                if (s == 1023) {
                    cm_out[d * 1024 + e0 + tid] = c_lds[tid];
                    hs_out[d * 1024 + e0 + tid] = h_lds[tid];
                }
            }
        }
    }
}

// ---------------------------------------------------------------------------
extern "C" void kernel_launch(void* const* d_in, const int* in_sizes, int n_in,
                              void* d_out, int out_size, void* d_ws, size_t ws_size,
                              hipStream_t stream) {
    (void)in_sizes; (void)n_in; (void)out_size; (void)ws_size;

    const float* x       = (const float*)d_in[0];
    const float* fw0_Wih = (const float*)d_in[1];
    const float* fw0_Whh = (const float*)d_in[2];
    const float* fw0_bih = (const float*)d_in[3];
    const float* fw0_bhh = (const float*)d_in[4];
    const float* fw1_Wih = (const float*)d_in[5];
    const float* fw1_Whh = (const float*)d_in[6];
    const float* fw1_bih = (const float*)d_in[7];
    const float* fw1_bhh = (const float*)d_in[8];
    const float* bw0_Wih = (const float*)d_in[9];
    const float* bw0_Whh = (const float*)d_in[10];
    const float* bw0_bih = (const float*)d_in[11];
    const float* bw0_bhh = (const float*)d_in[12];
    const float* bw1_Wih = (const float*)d_in[13];
    const float* bw1_Whh = (const float*)d_in[14];
    const float* bw1_bih = (const float*)d_in[15];
    const float* bw1_bhh = (const float*)d_in[16];

    char* ws = (char*)d_ws;
    u16* precomp = (u16*)ws;                      // [2][1024][4096] bf16 = 16 MB
    u64* htag0   = (u64*)(ws + (16 << 20));       // [2][1024][256]       =  4 MB
    u64* htag1   = (u64*)(ws + (20 << 20));       // [2][1024][256]       =  4 MB
    u32* cnt     = (u32*)(ws + (24 << 20));       // [4][1024][32] u32    = 512 KB
    float* out   = (float*)d_out;

    // Invalidate htag0+htag1+cnt (contiguous from +16MB).
    hipMemsetAsync(htag0, 0, ((size_t)8 << 20) + ((size_t)512 << 10), stream);

    dim3 g(8, 32);
    gemm_ih<<<g, 256, 0, stream>>>(x, fw0_Wih, fw0_bih, fw0_bhh, precomp, 768);
    gemm_ih<<<g, 256, 0, stream>>>(x, bw0_Wih, bw0_bih, bw0_bhh,
                                   precomp + (size_t)1024 * 4096, 768);

    lstm_fused<<<512, 256, 76096, stream>>>(
        fw0_Whh, bw0_Whh, fw1_Whh, bw1_Whh, fw1_Wih, bw1_Wih,
        fw1_bih, fw1_bhh, bw1_bih, bw1_bhh,
        precomp, htag0, htag1, cnt, out);
}

// Round 7
// 3419.871 us; speedup vs baseline: 1.7292x; 1.7292x over previous
//
#include <hip/hip_runtime.h>

typedef unsigned int u32;
typedef unsigned short u16;
typedef unsigned long long u64;
typedef __attribute__((ext_vector_type(8))) short v8s;   // 8 bf16
typedef __attribute__((ext_vector_type(4))) float v4f;

#define VALIDMASK 0x0001000100010001ULL

__device__ __forceinline__ float bf2f(u16 v) { return __uint_as_float(((u32)v) << 16); }
__device__ __forceinline__ u16 f2bf(float f) {
    u32 u = __float_as_uint(f);
    return (u16)((u + 0x7fffu + ((u >> 16) & 1u)) >> 16);   // RNE
}
// truncate-to-odd bf16: LSB always 1 (valid bit), |err| <= 1 ulp
__device__ __forceinline__ u32 f2bfo(float f) { return (__float_as_uint(f) >> 16) | 1u; }
__device__ __forceinline__ float sigf(float x) { return 1.0f / (1.0f + __expf(-x)); }
__device__ __forceinline__ float tanhfast(float x) {
    float e = __expf(2.0f * x);
    return 1.0f - 2.0f / (e + 1.0f);
}
__device__ __forceinline__ v8s pack8(v4f a, v4f b) {
    v8s r;
    r[0] = (short)f2bf(a[0]); r[1] = (short)f2bf(a[1]);
    r[2] = (short)f2bf(a[2]); r[3] = (short)f2bf(a[3]);
    r[4] = (short)f2bf(b[0]); r[5] = (short)f2bf(b[1]);
    r[6] = (short)f2bf(b[2]); r[7] = (short)f2bf(b[3]);
    return r;
}

// ---------------------------------------------------------------------------
// GEMM: out[t][j] = sum_k A[t][k]*W[j][k] + bih[j] + bhh[j]. fp32 in, bf16 out.
// Layer-0 input projections only (K=768).
// ---------------------------------------------------------------------------
__global__ __launch_bounds__(256) void gemm_ih(
    const float* __restrict__ A, const float* __restrict__ W,
    const float* __restrict__ bih, const float* __restrict__ bhh,
    u16* __restrict__ out, int K)
{
    __shared__ u16 As[128][40];
    __shared__ u16 Bs[128][40];
    const int tm = blockIdx.x, tn = blockIdx.y;
    const int tid = threadIdx.x;
    const int lane = tid & 63;
    const int wv = tid >> 6;
    const int wm = wv >> 1, wn = wv & 1;
    const int fr = lane & 15, fq = lane >> 4;

    v4f acc[4][4] = {};

    for (int kt = 0; kt < K; kt += 32) {
#pragma unroll
        for (int it = 0; it < 2; ++it) {
            int q = tid + it * 256;
            int r = q >> 2;
            int c8 = (q & 3) * 8;
            const float* pa = &A[(size_t)(tm * 128 + r) * K + kt + c8];
            const float* pw = &W[(size_t)(tn * 128 + r) * K + kt + c8];
            *(v8s*)&As[r][c8] = pack8(*(const v4f*)pa, *(const v4f*)(pa + 4));
            *(v8s*)&Bs[r][c8] = pack8(*(const v4f*)pw, *(const v4f*)(pw + 4));
        }
        __syncthreads();
        v8s af[4], bfr[4];
#pragma unroll
        for (int mi = 0; mi < 4; ++mi)
            af[mi] = *(const v8s*)&As[wm * 64 + mi * 16 + fr][fq * 8];
#pragma unroll
        for (int ni = 0; ni < 4; ++ni)
            bfr[ni] = *(const v8s*)&Bs[wn * 64 + ni * 16 + fr][fq * 8];
#pragma unroll
        for (int mi = 0; mi < 4; ++mi)
#pragma unroll
            for (int ni = 0; ni < 4; ++ni)
                acc[mi][ni] = __builtin_amdgcn_mfma_f32_16x16x32_bf16(af[mi], bfr[ni], acc[mi][ni], 0, 0, 0);
        __syncthreads();
    }

#pragma unroll
    for (int ni = 0; ni < 4; ++ni) {
        int col = tn * 128 + wn * 64 + ni * 16 + fr;
        float bias = bih[col] + bhh[col];
#pragma unroll
        for (int mi = 0; mi < 4; ++mi)
#pragma unroll
            for (int j = 0; j < 4; ++j) {
                int row = tm * 128 + wm * 64 + mi * 16 + fq * 4 + j;
                out[(size_t)row * 4096 + col] = f2bf(acc[mi][ni][j] + bias);
            }
    }
}

// ---------------------------------------------------------------------------
// Fused persistent bidirectional 2-layer LSTM scan. 512 WGs x 64 threads
// (ONE wave per WG -> no __syncthreads anywhere). role = bid>>8 (0:L0, 1:L1),
// d = (bid>>7)&1, wg = bid&127, e0 = wg*8 (8 owned h-elements = 32 rows).
// Whh rows live in 256 VGPRs as pre-packed 16x16x32 MFMA A-fragments; dot =
// 32 broadcast ds_read_b128 (B) + 64 MFMA, K-reduce inside MFMA. L1 holds
// Wih1 in LDS (XOR-swizzled) and consumes h0 from L0's broadcast. Broadcast:
// 4 odd-LSB bf16 per u64 (LSB = valid bit), relaxed agent atomics.
// MFMA frags: A row=lane&15(+16t), k=(lane>>4)*8+j; B col=lane&15 (broadcast
// across cols), k=(lane>>4)*8+j; D col=lane&15, row=(lane>>4)*4+reg.
// ---------------------------------------------------------------------------
__global__ __launch_bounds__(64, 1) void lstm_fused(
    const float* __restrict__ fw0_Whh, const float* __restrict__ bw0_Whh,
    const float* __restrict__ fw1_Whh, const float* __restrict__ bw1_Whh,
    const float* __restrict__ fw1_Wih, const float* __restrict__ bw1_Wih,
    const float* __restrict__ fw1_bih, const float* __restrict__ fw1_bhh,
    const float* __restrict__ bw1_bih, const float* __restrict__ bw1_bhh,
    const u16*  __restrict__ precomp0,   // [2][1024][4096] bf16
    u64* htag0,                          // [2][1024][256]
    u64* htag1,                          // [2][1024][256]
    float* __restrict__ out)             // d_out base
{
    extern __shared__ char smem[];       // [0,64K): Wih (L1). +64K: hA 2K,
    char* hA = smem + 65536;             // +66K: hB 2K, +68K: gd 128B
    char* hB = smem + 65536 + 2048;
    float* gd = (float*)(smem + 65536 + 4096);

    const int lane = threadIdx.x;
    const int bid = blockIdx.x;
    const int role = bid >> 8;
    const int sub = bid & 255;
    const int d = sub >> 7;
    const int wg = sub & 127;
    const int e0 = wg << 3;

    const float* __restrict__ Whh =
        role ? (d ? bw1_Whh : fw1_Whh) : (d ? bw0_Whh : fw0_Whh);

    // ---- Whh -> 64 A-fragments in registers (2 tiles x 32 K-chunks) ----
    v8s awf0[32], awf1[32];
    {
        int r0 = lane & 15, r1 = r0 + 16;
        int kq = (lane >> 4) << 3;
        const float* q0 = &Whh[(size_t)((r0 >> 3) * 1024 + e0 + (r0 & 7)) * 1024 + kq];
        const float* q1 = &Whh[(size_t)((r1 >> 3) * 1024 + e0 + (r1 & 7)) * 1024 + kq];
#pragma unroll
        for (int c = 0; c < 32; ++c) {
            awf0[c] = pack8(*(const v4f*)(q0 + 32 * c), *(const v4f*)(q0 + 32 * c + 4));
            awf1[c] = pack8(*(const v4f*)(q1 + 32 * c), *(const v4f*)(q1 + 32 * c + 4));
        }
    }

    // ---- L1: Wih1 slice -> LDS bf16 [32][1024], XOR-swizzled; biases ----
    float bias_i = 0.f, bias_f = 0.f, bias_g = 0.f, bias_o = 0.f;
    if (role) {
        const float* __restrict__ Wih = d ? bw1_Wih : fw1_Wih;
        for (int i = 0; i < 64; ++i) {
            int q = lane + (i << 6);             // 0..4095 16B-chunks
            int row = q >> 7;                    // 0..31
            int kb = (q & 127) << 4;             // byte within row
            const float* p = &Wih[(size_t)((row >> 3) * 1024 + e0 + (row & 7)) * 1024 + (kb >> 1)];
            int addr = (row << 11) + kb;
            addr ^= ((row & 7) << 4);
            *(v8s*)(smem + addr) = pack8(*(const v4f*)p, *(const v4f*)(p + 4));
        }
        if (lane < 8) {
            const float* bi = d ? bw1_bih : fw1_bih;
            const float* bh = d ? bw1_bhh : fw1_bhh;
            bias_i = bi[e0 + lane]        + bh[e0 + lane];
            bias_f = bi[1024 + e0 + lane] + bh[1024 + e0 + lane];
            bias_g = bi[2048 + e0 + lane] + bh[2048 + e0 + lane];
            bias_o = bi[3072 + e0 + lane] + bh[3072 + e0 + lane];
        }
    }

    u64* hown = (role ? htag1 : htag0) + (size_t)d * 1024 * 256;
    u64* hin  = htag0 + (size_t)d * 1024 * 256;
    float* cm_out = out + role * 2048;
    float* hs_out = out + 4096 + role * 2048;
    float* seq_out = out + 8192;                 // [1024][2048], L1 writes

    float c_state = 0.0f;                        // lanes 0..7 own element e0+lane

    for (int s = 0; s < 1024; ++s) {
        v4f acc0 = {0.f, 0.f, 0.f, 0.f}, acc1 = {0.f, 0.f, 0.f, 0.f};

        // L0: prefetch precomp row early (latency hides under poll/MFMA)
        u16 ri = 0, rf = 0, rg = 0, ro = 0;
        if (!role && lane < 8) {
            int sx = d ? (1023 - s) : s;
            const u16* pr = precomp0 + ((size_t)d * 1024 + sx) * 4096 + e0 + lane;
            ri = pr[0]; rf = pr[1024]; rg = pr[2048]; ro = pr[3072];
        }

        if (role) {   // ---- Wih1 @ h0[s]  (h0 arrives early; off critical loop)
            u64* p = hin + (size_t)s * 256 + (lane << 2);
            u64 a, b, c2, d2;
            for (;;) {
                a  = __hip_atomic_load(&p[0], __ATOMIC_RELAXED, __HIP_MEMORY_SCOPE_AGENT);
                b  = __hip_atomic_load(&p[1], __ATOMIC_RELAXED, __HIP_MEMORY_SCOPE_AGENT);
                c2 = __hip_atomic_load(&p[2], __ATOMIC_RELAXED, __HIP_MEMORY_SCOPE_AGENT);
                d2 = __hip_atomic_load(&p[3], __ATOMIC_RELAXED, __HIP_MEMORY_SCOPE_AGENT);
                if ((((a & b) & (c2 & d2)) & VALIDMASK) == VALIDMASK) break;
                __builtin_amdgcn_s_sleep(1);
            }
            *(u64*)(hB + (lane << 5))      = a;
            *(u64*)(hB + (lane << 5) + 8)  = b;
            *(u64*)(hB + (lane << 5) + 16) = c2;
            *(u64*)(hB + (lane << 5) + 24) = d2;
            asm volatile("s_waitcnt lgkmcnt(0)" ::: "memory");
            int r0 = lane & 15;
            int sw = (r0 & 7) << 4;
#pragma unroll
            for (int c = 0; c < 32; ++c) {
                int kb = (c << 6) + ((lane >> 4) << 4);
                v8s bfr = *(const v8s*)(hB + kb);
                v8s a0 = *(const v8s*)(smem + (((r0 << 11) + kb) ^ sw));
                v8s a1 = *(const v8s*)(smem + ((((r0 + 16) << 11) + kb) ^ sw));
                acc0 = __builtin_amdgcn_mfma_f32_16x16x32_bf16(a0, bfr, acc0, 0, 0, 0);
                acc1 = __builtin_amdgcn_mfma_f32_16x16x32_bf16(a1, bfr, acc1, 0, 0, 0);
            }
        }

        if (s > 0) {  // ---- Whh @ h_own[s-1]  (the critical recurrence)
            u64* p = hown + (size_t)(s - 1) * 256 + (lane << 2);
            u64 a, b, c2, d2;
            for (;;) {
                a  = __hip_atomic_load(&p[0], __ATOMIC_RELAXED, __HIP_MEMORY_SCOPE_AGENT);
                b  = __hip_atomic_load(&p[1], __ATOMIC_RELAXED, __HIP_MEMORY_SCOPE_AGENT);
                c2 = __hip_atomic_load(&p[2], __ATOMIC_RELAXED, __HIP_MEMORY_SCOPE_AGENT);
                d2 = __hip_atomic_load(&p[3], __ATOMIC_RELAXED, __HIP_MEMORY_SCOPE_AGENT);
                if ((((a & b) & (c2 & d2)) & VALIDMASK) == VALIDMASK) break;
                __builtin_amdgcn_s_sleep(1);
            }
            *(u64*)(hA + (lane << 5))      = a;
            *(u64*)(hA + (lane << 5) + 8)  = b;
            *(u64*)(hA + (lane << 5) + 16) = c2;
            *(u64*)(hA + (lane << 5) + 24) = d2;
            asm volatile("s_waitcnt lgkmcnt(0)" ::: "memory");
#pragma unroll
            for (int c = 0; c < 32; ++c) {
                v8s bfr = *(const v8s*)(hA + (c << 6) + ((lane >> 4) << 4));
                acc0 = __builtin_amdgcn_mfma_f32_16x16x32_bf16(awf0[c], bfr, acc0, 0, 0, 0);
                acc1 = __builtin_amdgcn_mfma_f32_16x16x32_bf16(awf1[c], bfr, acc1, 0, 0, 0);
            }
        }

        // ---- gates: D col 0..15 all equal; col0 lanes dump 32 gate sums ----
        if ((lane & 15) == 0) {
            int rbase = (lane >> 4) << 2;        // 0,4,8,12
            *(v4f*)&gd[rbase]      = acc0;       // rows 0..15  (i, f)
            *(v4f*)&gd[16 + rbase] = acc1;       // rows 16..31 (g, o)
        }
        asm volatile("s_waitcnt lgkmcnt(0)" ::: "memory");

        float h_new = 0.0f;
        if (lane < 8) {
            float Gi = gd[lane]      + (role ? bias_i : bf2f(ri));
            float Gf = gd[8 + lane]  + (role ? bias_f : bf2f(rf));
            float Gg = gd[16 + lane] + (role ? bias_g : bf2f(rg));
            float Go = gd[24 + lane] + (role ? bias_o : bf2f(ro));
            c_state = sigf(Gf) * c_state + sigf(Gi) * tanhfast(Gg);
            h_new = sigf(Go) * tanhfast(c_state);
        }

        // ---- publish: gather 8 h -> 2 u64 (4 odd-LSB bf16 each) ----
        u32 w0 = f2bfo(__shfl(h_new, (lane << 2)))     | (f2bfo(__shfl(h_new, (lane << 2) + 1)) << 16);
        u32 w1 = f2bfo(__shfl(h_new, (lane << 2) + 2)) | (f2bfo(__shfl(h_new, (lane << 2) + 3)) << 16);
        if (lane < 2) {
            u64 val = ((u64)w1 << 32) | w0;
            __hip_atomic_store(&hown[(size_t)s * 256 + (e0 >> 2) + lane], val,
                               __ATOMIC_RELAXED, __HIP_MEMORY_SCOPE_AGENT);
        }

        if (lane < 8) {
            if (role) {
                int rrow = d ? (1023 - s) : s;
                seq_out[(size_t)rrow * 2048 + d * 1024 + e0 + lane] = h_new;
            }
            if (s == 1023) {
                cm_out[d * 1024 + e0 + lane] = c_state;
                hs_out[d * 1024 + e0 + lane] = h_new;
            }
        }
    }
}

// ---------------------------------------------------------------------------
extern "C" void kernel_launch(void* const* d_in, const int* in_sizes, int n_in,
                              void* d_out, int out_size, void* d_ws, size_t ws_size,
                              hipStream_t stream) {
    (void)in_sizes; (void)n_in; (void)out_size; (void)ws_size;

    const float* x       = (const float*)d_in[0];
    const float* fw0_Wih = (const float*)d_in[1];
    const float* fw0_Whh = (const float*)d_in[2];
    const float* fw0_bih = (const float*)d_in[3];
    const float* fw0_bhh = (const float*)d_in[4];
    const float* fw1_Wih = (const float*)d_in[5];
    const float* fw1_Whh = (const float*)d_in[6];
    const float* fw1_bih = (const float*)d_in[7];
    const float* fw1_bhh = (const float*)d_in[8];
    const float* bw0_Wih = (const float*)d_in[9];
    const float* bw0_Whh = (const float*)d_in[10];
    const float* bw0_bih = (const float*)d_in[11];
    const float* bw0_bhh = (const float*)d_in[12];
    const float* bw1_Wih = (const float*)d_in[13];
    const float* bw1_Whh = (const float*)d_in[14];
    const float* bw1_bih = (const float*)d_in[15];
    const float* bw1_bhh = (const float*)d_in[16];

    char* ws = (char*)d_ws;
    u16* precomp = (u16*)ws;                      // [2][1024][4096] bf16 = 16 MB
    u64* htag0   = (u64*)(ws + (16 << 20));       // [2][1024][256]       =  4 MB
    u64* htag1   = (u64*)(ws + (20 << 20));       // [2][1024][256]       =  4 MB
    float* out   = (float*)d_out;

    hipMemsetAsync(htag0, 0, (size_t)8 << 20, stream);   // invalidate both

    dim3 g(8, 32);
    gemm_ih<<<g, 256, 0, stream>>>(x, fw0_Wih, fw0_bih, fw0_bhh, precomp, 768);
    gemm_ih<<<g, 256, 0, stream>>>(x, bw0_Wih, bw0_bih, bw0_bhh,
                                   precomp + (size_t)1024 * 4096, 768);

    lstm_fused<<<512, 64, 69760, stream>>>(
        fw0_Whh, bw0_Whh, fw1_Whh, bw1_Whh, fw1_Wih, bw1_Wih,
        fw1_bih, fw1_bhh, bw1_bih, bw1_bhh,
        precomp, htag0, htag1, out);
}

// Round 8
// 3415.741 us; speedup vs baseline: 1.7313x; 1.0012x over previous
//
#include <hip/hip_runtime.h>

typedef unsigned int u32;
typedef unsigned short u16;
typedef unsigned long long u64;
typedef __attribute__((ext_vector_type(8))) short v8s;   // 8 bf16
typedef __attribute__((ext_vector_type(4))) float v4f;

#define VALIDMASK 0x0001000100010001ULL

__device__ __forceinline__ float bf2f(u16 v) { return __uint_as_float(((u32)v) << 16); }
__device__ __forceinline__ u16 f2bf(float f) {
    u32 u = __float_as_uint(f);
    return (u16)((u + 0x7fffu + ((u >> 16) & 1u)) >> 16);   // RNE
}
// truncate-to-odd bf16: LSB always 1 (valid bit), |err| <= 1 ulp
__device__ __forceinline__ u32 f2bfo(float f) { return (__float_as_uint(f) >> 16) | 1u; }
__device__ __forceinline__ float sigf(float x) { return 1.0f / (1.0f + __expf(-x)); }
__device__ __forceinline__ float tanhfast(float x) {
    float e = __expf(2.0f * x);
    return 1.0f - 2.0f / (e + 1.0f);
}
__device__ __forceinline__ v8s pack8(v4f a, v4f b) {
    v8s r;
    r[0] = (short)f2bf(a[0]); r[1] = (short)f2bf(a[1]);
    r[2] = (short)f2bf(a[2]); r[3] = (short)f2bf(a[3]);
    r[4] = (short)f2bf(b[0]); r[5] = (short)f2bf(b[1]);
    r[6] = (short)f2bf(b[2]); r[7] = (short)f2bf(b[3]);
    return r;
}

// ---------------------------------------------------------------------------
// GEMM: out[t][j] = sum_k A[t][k]*W[j][k] + bih[j] + bhh[j]. fp32 in, bf16 out.
// Layer-0 input projections only (K=768).
// ---------------------------------------------------------------------------
__global__ __launch_bounds__(256) void gemm_ih(
    const float* __restrict__ A, const float* __restrict__ W,
    const float* __restrict__ bih, const float* __restrict__ bhh,
    u16* __restrict__ out, int K)
{
    __shared__ u16 As[128][40];
    __shared__ u16 Bs[128][40];
    const int tm = blockIdx.x, tn = blockIdx.y;
    const int tid = threadIdx.x;
    const int lane = tid & 63;
    const int wv = tid >> 6;
    const int wm = wv >> 1, wn = wv & 1;
    const int fr = lane & 15, fq = lane >> 4;

    v4f acc[4][4] = {};

    for (int kt = 0; kt < K; kt += 32) {
#pragma unroll
        for (int it = 0; it < 2; ++it) {
            int q = tid + it * 256;
            int r = q >> 2;
            int c8 = (q & 3) * 8;
            const float* pa = &A[(size_t)(tm * 128 + r) * K + kt + c8];
            const float* pw = &W[(size_t)(tn * 128 + r) * K + kt + c8];
            *(v8s*)&As[r][c8] = pack8(*(const v4f*)pa, *(const v4f*)(pa + 4));
            *(v8s*)&Bs[r][c8] = pack8(*(const v4f*)pw, *(const v4f*)(pw + 4));
        }
        __syncthreads();
        v8s af[4], bfr[4];
#pragma unroll
        for (int mi = 0; mi < 4; ++mi)
            af[mi] = *(const v8s*)&As[wm * 64 + mi * 16 + fr][fq * 8];
#pragma unroll
        for (int ni = 0; ni < 4; ++ni)
            bfr[ni] = *(const v8s*)&Bs[wn * 64 + ni * 16 + fr][fq * 8];
#pragma unroll
        for (int mi = 0; mi < 4; ++mi)
#pragma unroll
            for (int ni = 0; ni < 4; ++ni)
                acc[mi][ni] = __builtin_amdgcn_mfma_f32_16x16x32_bf16(af[mi], bfr[ni], acc[mi][ni], 0, 0, 0);
        __syncthreads();
    }

#pragma unroll
    for (int ni = 0; ni < 4; ++ni) {
        int col = tn * 128 + wn * 64 + ni * 16 + fr;
        float bias = bih[col] + bhh[col];
#pragma unroll
        for (int mi = 0; mi < 4; ++mi)
#pragma unroll
            for (int j = 0; j < 4; ++j) {
                int row = tm * 128 + wm * 64 + mi * 16 + fq * 4 + j;
                out[(size_t)row * 4096 + col] = f2bf(acc[mi][ni][j] + bias);
            }
    }
}

// ---------------------------------------------------------------------------
// Fused persistent bidirectional 2-layer LSTM scan. 512 WGs x 64 threads
// (ONE wave per WG -> no __syncthreads anywhere). role = bid>>8 (0:L0, 1:L1),
// d = (bid>>7)&1, wg = bid&127, e0 = wg*8 (8 owned h-elements = 32 rows).
// Whh rows live in 256 VGPRs as pre-packed 16x16x32 MFMA A-fragments; dot =
// 32 broadcast ds_read_b128 (B) + 64 MFMA, K-reduce inside MFMA. L1 holds
// Wih1 in LDS (XOR-swizzled) and consumes h0 from L0's broadcast. Broadcast:
// 4 odd-LSB bf16 per u64 (LSB = valid bit), relaxed agent atomics.
// MFMA frags: A row=lane&15(+16t), k=(lane>>4)*8+j; B col=lane&15 (broadcast
// across cols), k=(lane>>4)*8+j; D col=lane&15, row=(lane>>4)*4+reg.
// ---------------------------------------------------------------------------
__global__ __launch_bounds__(64, 1) void lstm_fused(
    const float* __restrict__ fw0_Whh, const float* __restrict__ bw0_Whh,
    const float* __restrict__ fw1_Whh, const float* __restrict__ bw1_Whh,
    const float* __restrict__ fw1_Wih, const float* __restrict__ bw1_Wih,
    const float* __restrict__ fw1_bih, const float* __restrict__ fw1_bhh,
    const float* __restrict__ bw1_bih, const float* __restrict__ bw1_bhh,
    const u16*  __restrict__ precomp0,   // [2][1024][4096] bf16
    u64* htag0,                          // [2][1024][256]
    u64* htag1,                          // [2][1024][256]
    float* __restrict__ out)             // d_out base
{
    extern __shared__ char smem[];       // [0,64K): Wih (L1). +64K: hA 2K,
    char* hA = smem + 65536;             // +66K: hB 2K, +68K: gd 128B
    char* hB = smem + 65536 + 2048;
    float* gd = (float*)(smem + 65536 + 4096);

    const int lane = threadIdx.x;
    const int bid = blockIdx.x;
    const int role = bid >> 8;
    const int sub = bid & 255;
    const int d = sub >> 7;
    const int wg = sub & 127;
    const int e0 = wg << 3;

    const float* __restrict__ Whh =
        role ? (d ? bw1_Whh : fw1_Whh) : (d ? bw0_Whh : fw0_Whh);

    // ---- Whh -> 64 A-fragments in registers (2 tiles x 32 K-chunks) ----
    v8s awf0[32], awf1[32];
    {
        int r0 = lane & 15, r1 = r0 + 16;
        int kq = (lane >> 4) << 3;
        const float* q0 = &Whh[(size_t)((r0 >> 3) * 1024 + e0 + (r0 & 7)) * 1024 + kq];
        const float* q1 = &Whh[(size_t)((r1 >> 3) * 1024 + e0 + (r1 & 7)) * 1024 + kq];
#pragma unroll
        for (int c = 0; c < 32; ++c) {
            awf0[c] = pack8(*(const v4f*)(q0 + 32 * c), *(const v4f*)(q0 + 32 * c + 4));
            awf1[c] = pack8(*(const v4f*)(q1 + 32 * c), *(const v4f*)(q1 + 32 * c + 4));
        }
    }

    // ---- L1: Wih1 slice -> LDS bf16 [32][1024], XOR-swizzled; biases ----
    float bias_i = 0.f, bias_f = 0.f, bias_g = 0.f, bias_o = 0.f;
    if (role) {
        const float* __restrict__ Wih = d ? bw1_Wih : fw1_Wih;
        for (int i = 0; i < 64; ++i) {
            int q = lane + (i << 6);             // 0..4095 16B-chunks
            int row = q >> 7;                    // 0..31
            int kb = (q & 127) << 4;             // byte within row
            const float* p = &Wih[(size_t)((row >> 3) * 1024 + e0 + (row & 7)) * 1024 + (kb >> 1)];
            int addr = (row << 11) + kb;
            addr ^= ((row & 7) << 4);
            *(v8s*)(smem + addr) = pack8(*(const v4f*)p, *(const v4f*)(p + 4));
        }
        if (lane < 8) {
            const float* bi = d ? bw1_bih : fw1_bih;
            const float* bh = d ? bw1_bhh : fw1_bhh;
            bias_i = bi[e0 + lane]        + bh[e0 + lane];
            bias_f = bi[1024 + e0 + lane] + bh[1024 + e0 + lane];
            bias_g = bi[2048 + e0 + lane] + bh[2048 + e0 + lane];
            bias_o = bi[3072 + e0 + lane] + bh[3072 + e0 + lane];
        }
    }

    u64* hown = (role ? htag1 : htag0) + (size_t)d * 1024 * 256;
    u64* hin  = htag0 + (size_t)d * 1024 * 256;
    float* cm_out = out + role * 2048;
    float* hs_out = out + 4096 + role * 2048;
    float* seq_out = out + 8192;                 // [1024][2048], L1 writes

    float c_state = 0.0f;                        // lanes 0..7 own element e0+lane

    for (int s = 0; s < 1024; ++s) {
        v4f acc0 = {0.f, 0.f, 0.f, 0.f}, acc1 = {0.f, 0.f, 0.f, 0.f};

        // L0: prefetch precomp row early (latency hides under poll/MFMA)
        u16 ri = 0, rf = 0, rg = 0, ro = 0;
        if (!role && lane < 8) {
            int sx = d ? (1023 - s) : s;
            const u16* pr = precomp0 + ((size_t)d * 1024 + sx) * 4096 + e0 + lane;
            ri = pr[0]; rf = pr[1024]; rg = pr[2048]; ro = pr[3072];
        }

        if (role) {   // ---- Wih1 @ h0[s]  (h0 arrives early; off critical loop)
            u64* p = hin + (size_t)s * 256 + (lane << 2);
            u64 a, b, c2, d2;
            for (;;) {
                a  = __hip_atomic_load(&p[0], __ATOMIC_RELAXED, __HIP_MEMORY_SCOPE_AGENT);
                b  = __hip_atomic_load(&p[1], __ATOMIC_RELAXED, __HIP_MEMORY_SCOPE_AGENT);
                c2 = __hip_atomic_load(&p[2], __ATOMIC_RELAXED, __HIP_MEMORY_SCOPE_AGENT);
                d2 = __hip_atomic_load(&p[3], __ATOMIC_RELAXED, __HIP_MEMORY_SCOPE_AGENT);
                if ((((a & b) & (c2 & d2)) & VALIDMASK) == VALIDMASK) break;
                __builtin_amdgcn_s_sleep(1);
            }
            *(u64*)(hB + (lane << 5))      = a;
            *(u64*)(hB + (lane << 5) + 8)  = b;
            *(u64*)(hB + (lane << 5) + 16) = c2;
            *(u64*)(hB + (lane << 5) + 24) = d2;
            asm volatile("s_waitcnt lgkmcnt(0)" ::: "memory");
            int r0 = lane & 15;
            int sw = (r0 & 7) << 4;
#pragma unroll
            for (int c = 0; c < 32; ++c) {
                int kb = (c << 6) + ((lane >> 4) << 4);
                v8s bfr = *(const v8s*)(hB + kb);
                v8s a0 = *(const v8s*)(smem + (((r0 << 11) + kb) ^ sw));
                v8s a1 = *(const v8s*)(smem + ((((r0 + 16) << 11) + kb) ^ sw));
                acc0 = __builtin_amdgcn_mfma_f32_16x16x32_bf16(a0, bfr, acc0, 0, 0, 0);
                acc1 = __builtin_amdgcn_mfma_f32_16x16x32_bf16(a1, bfr, acc1, 0, 0, 0);
            }
        }

        if (s > 0) {  // ---- Whh @ h_own[s-1]  (the critical recurrence)
            u64* p = hown + (size_t)(s - 1) * 256 + (lane << 2);
            u64 a, b, c2, d2;
            for (;;) {
                a  = __hip_atomic_load(&p[0], __ATOMIC_RELAXED, __HIP_MEMORY_SCOPE_AGENT);
                b  = __hip_atomic_load(&p[1], __ATOMIC_RELAXED, __HIP_MEMORY_SCOPE_AGENT);
                c2 = __hip_atomic_load(&p[2], __ATOMIC_RELAXED, __HIP_MEMORY_SCOPE_AGENT);
                d2 = __hip_atomic_load(&p[3], __ATOMIC_RELAXED, __HIP_MEMORY_SCOPE_AGENT);
                if ((((a & b) & (c2 & d2)) & VALIDMASK) == VALIDMASK) break;
                __builtin_amdgcn_s_sleep(1);
            }
            *(u64*)(hA + (lane << 5))      = a;
            *(u64*)(hA + (lane << 5) + 8)  = b;
            *(u64*)(hA + (lane << 5) + 16) = c2;
            *(u64*)(hA + (lane << 5) + 24) = d2;
            asm volatile("s_waitcnt lgkmcnt(0)" ::: "memory");
#pragma unroll
            for (int c = 0; c < 32; ++c) {
                v8s bfr = *(const v8s*)(hA + (c << 6) + ((lane >> 4) << 4));
                acc0 = __builtin_amdgcn_mfma_f32_16x16x32_bf16(awf0[c], bfr, acc0, 0, 0, 0);
                acc1 = __builtin_amdgcn_mfma_f32_16x16x32_bf16(awf1[c], bfr, acc1, 0, 0, 0);
            }
        }

        // ---- gates: D col 0..15 all equal; col0 lanes dump 32 gate sums ----
        if ((lane & 15) == 0) {
            int rbase = (lane >> 4) << 2;        // 0,4,8,12
            *(v4f*)&gd[rbase]      = acc0;       // rows 0..15  (i, f)
            *(v4f*)&gd[16 + rbase] = acc1;       // rows 16..31 (g, o)
        }
        asm volatile("s_waitcnt lgkmcnt(0)" ::: "memory");

        float h_new = 0.0f;
        if (lane < 8) {
            float Gi = gd[lane]      + (role ? bias_i : bf2f(ri));
            float Gf = gd[8 + lane]  + (role ? bias_f : bf2f(rf));
            float Gg = gd[16 + lane] + (role ? bias_g : bf2f(rg));
            float Go = gd[24 + lane] + (role ? bias_o : bf2f(ro));
            c_state = sigf(Gf) * c_state + sigf(Gi) * tanhfast(Gg);
            h_new = sigf(Go) * tanhfast(c_state);
        }

        // ---- publish: gather 8 h -> 2 u64 (4 odd-LSB bf16 each) ----
        u32 w0 = f2bfo(__shfl(h_new, (lane << 2)))     | (f2bfo(__shfl(h_new, (lane << 2) + 1)) << 16);
        u32 w1 = f2bfo(__shfl(h_new, (lane << 2) + 2)) | (f2bfo(__shfl(h_new, (lane << 2) + 3)) << 16);
        if (lane < 2) {
            u64 val = ((u64)w1 << 32) | w0;
            __hip_atomic_store(&hown[(size_t)s * 256 + (e0 >> 2) + lane], val,
                               __ATOMIC_RELAXED, __HIP_MEMORY_SCOPE_AGENT);
        }

        if (lane < 8) {
            if (role) {
                int rrow = d ? (1023 - s) : s;
                seq_out[(size_t)rrow * 2048 + d * 1024 + e0 + lane] = h_new;
            }
            if (s == 1023) {
                cm_out[d * 1024 + e0 + lane] = c_state;
                hs_out[d * 1024 + e0 + lane] = h_new;
            }
        }
    }
}

// ---------------------------------------------------------------------------
extern "C" void kernel_launch(void* const* d_in, const int* in_sizes, int n_in,
                              void* d_out, int out_size, void* d_ws, size_t ws_size,
                              hipStream_t stream) {
    (void)in_sizes; (void)n_in; (void)out_size; (void)ws_size;

    const float* x       = (const float*)d_in[0];
    const float* fw0_Wih = (const float*)d_in[1];
    const float* fw0_Whh = (const float*)d_in[2];
    const float* fw0_bih = (const float*)d_in[3];
    const float* fw0_bhh = (const float*)d_in[4];
    const float* fw1_Wih = (const float*)d_in[5];
    const float* fw1_Whh = (const float*)d_in[6];
    const float* fw1_bih = (const float*)d_in[7];
    const float* fw1_bhh = (const float*)d_in[8];
    const float* bw0_Wih = (const float*)d_in[9];
    const float* bw0_Whh = (const float*)d_in[10];
    const float* bw0_bih = (const float*)d_in[11];
    const float* bw0_bhh = (const float*)d_in[12];
    const float* bw1_Wih = (const float*)d_in[13];
    const float* bw1_Whh = (const float*)d_in[14];
    const float* bw1_bih = (const float*)d_in[15];
    const float* bw1_bhh = (const float*)d_in[16];

    char* ws = (char*)d_ws;
    u16* precomp = (u16*)ws;                      // [2][1024][4096] bf16 = 16 MB
    u64* htag0   = (u64*)(ws + (16 << 20));       // [2][1024][256]       =  4 MB
    u64* htag1   = (u64*)(ws + (20 << 20));       // [2][1024][256]       =  4 MB
    float* out   = (float*)d_out;

    hipMemsetAsync(htag0, 0, (size_t)8 << 20, stream);   // invalidate both

    dim3 g(8, 32);
    gemm_ih<<<g, 256, 0, stream>>>(x, fw0_Wih, fw0_bih, fw0_bhh, precomp, 768);
    gemm_ih<<<g, 256, 0, stream>>>(x, bw0_Wih, bw0_bih, bw0_bhh,
                                   precomp + (size_t)1024 * 4096, 768);

    lstm_fused<<<512, 64, 69760, stream>>>(
        fw0_Whh, bw0_Whh, fw1_Whh, bw1_Whh, fw1_Wih, bw1_Wih,
        fw1_bih, fw1_bhh, bw1_bih, bw1_bhh,
        precomp, htag0, htag1, out);
}